// Round 5
// baseline (375.622 us; speedup 1.0000x reference)
//
#include <hip/hip_runtime.h>
#include <hip/hip_fp16.h>
#include <hip/hip_bf16.h>

#define NN 50000
#define EE 800000
#define NSWEEP 4
#define RANGE 12500           // src range per sweep: 12500*128B = 1.6MB (bf16) << 4MB XCD L2
#define NSEG 200000           // NSWEEP * NN segments
#define SCAN_BLKS 782         // ceil(NSEG/256)

// ---- workspace layout (proven-safe 12.8MB + flag envelope) ----
#define OFF_AGGH   0ull          // 50000*64*2 = 6,400,000
#define OFF_EID    6400000ull    // 800000*4  = 3,200,000  -> ends  9,600,000
#define OFF_SRC    9600000ull    // 800000*2  = 1,600,000  -> ends 11,200,000
#define OFF_CURSOR 11200000ull   // 200000*4  =   800,000  -> ends 12,000,000
#define OFF_PART   12000000ull   // 782*4     =     3,128  -> ends 12,003,128
#define OFF_FLAG   12800000ull   // proven-safe offset from prior session

__device__ __forceinline__ float bflo(unsigned u) { return __uint_as_float(u << 16); }
__device__ __forceinline__ float bfhi(unsigned u) { return __uint_as_float(u & 0xffff0000u); }

// zero cursor (grid-wide) + dtype-detect (block 0). flag=1 if bf16 (proven R3/R6).
__global__ __launch_bounds__(256) void zero_detect_kernel(const unsigned* __restrict__ xw,
                                                          int* __restrict__ cursor,
                                                          int* __restrict__ flag) {
    const int i = blockIdx.x * 256 + threadIdx.x;
    if (i < NSEG) cursor[i] = 0;
    if (blockIdx.x == 0 && threadIdx.x < 64) {
        const int t = threadIdx.x;
        unsigned e = (xw[t] >> 7) & 0xFFu;
        unsigned long long m = __ballot(e >= 100u && e <= 140u);
        if (t == 0) *flag = (__popcll(m) >= 32) ? 1 : 0;
    }
}

// edge_attr row (broadcast across wave) dot We column — plain cached loads (R3: never nt)
template <bool BF16>
__device__ __forceinline__ float edge_lin(const void* __restrict__ eav, int e,
                                          const float* __restrict__ we, float bed) {
    float acc = bed;
    if constexpr (BF16) {
        const uint4* row = (const uint4*)((const __hip_bfloat16*)eav + (size_t)e * 16);
        const uint4 p0 = row[0];
        const uint4 p1 = row[1];
        acc = fmaf(bflo(p0.x), we[0],  acc); acc = fmaf(bfhi(p0.x), we[1],  acc);
        acc = fmaf(bflo(p0.y), we[2],  acc); acc = fmaf(bfhi(p0.y), we[3],  acc);
        acc = fmaf(bflo(p0.z), we[4],  acc); acc = fmaf(bfhi(p0.z), we[5],  acc);
        acc = fmaf(bflo(p0.w), we[6],  acc); acc = fmaf(bfhi(p0.w), we[7],  acc);
        acc = fmaf(bflo(p1.x), we[8],  acc); acc = fmaf(bfhi(p1.x), we[9],  acc);
        acc = fmaf(bflo(p1.y), we[10], acc); acc = fmaf(bfhi(p1.y), we[11], acc);
        acc = fmaf(bflo(p1.z), we[12], acc); acc = fmaf(bfhi(p1.z), we[13], acc);
        acc = fmaf(bflo(p1.w), we[14], acc); acc = fmaf(bfhi(p1.w), we[15], acc);
    } else {
        const float4* row = (const float4*)((const float*)eav + (size_t)e * 16);
        const float4 q0 = row[0], q1 = row[1], q2 = row[2], q3 = row[3];
        acc = fmaf(q0.x, we[0],  acc); acc = fmaf(q0.y, we[1],  acc);
        acc = fmaf(q0.z, we[2],  acc); acc = fmaf(q0.w, we[3],  acc);
        acc = fmaf(q1.x, we[4],  acc); acc = fmaf(q1.y, we[5],  acc);
        acc = fmaf(q1.z, we[6],  acc); acc = fmaf(q1.w, we[7],  acc);
        acc = fmaf(q2.x, we[8],  acc); acc = fmaf(q2.y, we[9],  acc);
        acc = fmaf(q2.z, we[10], acc); acc = fmaf(q2.w, we[11], acc);
        acc = fmaf(q3.x, we[12], acc); acc = fmaf(q3.y, we[13], acc);
        acc = fmaf(q3.z, we[14], acc); acc = fmaf(q3.w, we[15], acc);
    }
    return acc;
}

// ---------------- histogram over (src-range, dst) ----------------
__global__ __launch_bounds__(256) void hist_kernel(const int* __restrict__ ei,
                                                   int* __restrict__ cnt) {
    const int oddor = ei[1] | ei[3] | ei[5] | ei[7] | ei[9] | ei[11] | ei[13] | ei[15];
    const bool idx64 = (oddor == 0);
    const long long* __restrict__ ei64 = (const long long*)ei;
    const int e = blockIdx.x * 256 + threadIdx.x;
    if (e < EE) {
        int src, dst;
        if (idx64) { src = (int)ei64[e]; dst = (int)ei64[EE + e]; }
        else       { src = ei[e];        dst = ei[EE + e]; }
        const int h = src / RANGE;                   // 0..3
        atomicAdd(&cnt[h * NN + dst], 1);
    }
}

// ---------------- scan A: per-block exclusive scan (in-place) + block totals ----------------
__global__ __launch_bounds__(256) void scanA_kernel(int* __restrict__ cursor,
                                                    int* __restrict__ part) {
    __shared__ int sdat[256];
    const int tid = threadIdx.x;
    const int ci  = blockIdx.x * 256 + tid;
    const int myc = (ci < NSEG) ? cursor[ci] : 0;
    sdat[tid] = myc;
    __syncthreads();
#pragma unroll
    for (int off = 1; off < 256; off <<= 1) {
        const int v = (tid >= off) ? sdat[tid - off] : 0;
        __syncthreads();
        sdat[tid] += v;
        __syncthreads();
    }
    if (ci < NSEG) cursor[ci] = sdat[tid] - myc;   // block-local exclusive
    if (tid == 255) part[blockIdx.x] = sdat[255];
}

// ---------------- scan BC: each block reduces its prefix of part[] and applies base ----------------
__global__ __launch_bounds__(256) void scanBC_kernel(const int* __restrict__ part,
                                                     int* __restrict__ cursor) {
    __shared__ int red[256];
    const int b = blockIdx.x, tid = threadIdx.x;
    int s = 0;
    for (int i = tid; i < b; i += 256) s += part[i];
    red[tid] = s;
    __syncthreads();
#pragma unroll
    for (int off = 128; off > 0; off >>= 1) {
        if (tid < off) red[tid] += red[tid + off];
        __syncthreads();
    }
    const int base = red[0];
    const int ci = b * 256 + tid;
    if (ci < NSEG) cursor[ci] += base;             // global exclusive prefix (cursor init)
}

// ---------------- scatter (eid, src) into (range, dst) segments ----------------
__global__ __launch_bounds__(256) void scatter_kernel(const int* __restrict__ ei,
                                                      int* __restrict__ cursor,
                                                      int* __restrict__ recs_eid,
                                                      unsigned short* __restrict__ recs_src) {
    const int oddor = ei[1] | ei[3] | ei[5] | ei[7] | ei[9] | ei[11] | ei[13] | ei[15];
    const bool idx64 = (oddor == 0);
    const long long* __restrict__ ei64 = (const long long*)ei;
    const int e = blockIdx.x * 256 + threadIdx.x;
    if (e < EE) {
        int src, dst;
        if (idx64) { src = (int)ei64[e]; dst = (int)ei64[EE + e]; }
        else       { src = ei[e];        dst = ei[EE + e]; }
        const int h = src / RANGE;
        const int p = atomicAdd(&cursor[h * NN + dst], 1);
        recs_eid[p] = e;
        recs_src[p] = (unsigned short)src;
    }
}

// ---------------- gather: NSWEEP src-range sweeps, one wave per node, no atomics ----------------
template <bool BF16>
__device__ __forceinline__ float loadx(const void* __restrict__ xv, int s, int d) {
    if constexpr (BF16)
        return __bfloat162float(((const __hip_bfloat16*)xv)[(size_t)s * 64 + d]);
    else
        return ((const float*)xv)[(size_t)s * 64 + d];
}

template <bool BF16>
__device__ __forceinline__ float seg_accum(
    const void* __restrict__ xv,
    const int* __restrict__ recs_eid, const unsigned short* __restrict__ recs_src,
    const void* __restrict__ eav, const float* __restrict__ we, float bed,
    int beg, int end, int d, float agg)
{
    int k = beg;
    for (; k + 4 <= end; k += 4) {
        const int e0 = recs_eid[k],     e1 = recs_eid[k + 1];
        const int e2 = recs_eid[k + 2], e3 = recs_eid[k + 3];
        const int s0 = (int)recs_src[k],     s1 = (int)recs_src[k + 1];
        const int s2 = (int)recs_src[k + 2], s3 = (int)recs_src[k + 3];
        const float x0 = loadx<BF16>(xv, s0, d);
        const float x1 = loadx<BF16>(xv, s1, d);
        const float x2 = loadx<BF16>(xv, s2, d);
        const float x3 = loadx<BF16>(xv, s3, d);
        const float a0 = edge_lin<BF16>(eav, e0, we, bed);
        const float a1 = edge_lin<BF16>(eav, e1, we, bed);
        const float a2 = edge_lin<BF16>(eav, e2, we, bed);
        const float a3 = edge_lin<BF16>(eav, e3, we, bed);
        agg += fmaxf(a0 + x0, 0.0f);
        agg += fmaxf(a1 + x1, 0.0f);
        agg += fmaxf(a2 + x2, 0.0f);
        agg += fmaxf(a3 + x3, 0.0f);
    }
    for (; k < end; ++k) {
        const int e0 = recs_eid[k];
        const int s0 = (int)recs_src[k];
        const float x0 = loadx<BF16>(xv, s0, d);
        agg += fmaxf(edge_lin<BF16>(eav, e0, we, bed) + x0, 0.0f);
    }
    return agg;
}

template <bool BF16>
__device__ __forceinline__ void gather_body(
    const void* __restrict__ xv,
    const int* __restrict__ recs_eid, const unsigned short* __restrict__ recs_src,
    const int* __restrict__ cursor,
    const void* __restrict__ eav, const void* __restrict__ Wev,
    const void* __restrict__ bev, __half* __restrict__ aggh)
{
    const int tid = threadIdx.x;
    const int d   = tid & 63;
    const int sub = tid >> 6;

    float we[16];
    float bed;
    if constexpr (BF16) {
        const __hip_bfloat16* We = (const __hip_bfloat16*)Wev;
#pragma unroll
        for (int k = 0; k < 16; k++) we[k] = __bfloat162float(We[k * 64 + d]);
        bed = __bfloat162float(((const __hip_bfloat16*)bev)[d]);
    } else {
        const float* We = (const float*)Wev;
#pragma unroll
        for (int k = 0; k < 16; k++) we[k] = We[k * 64 + d];
        bed = ((const float*)bev)[d];
    }

    const int wid = blockIdx.x * 4 + sub;
    const int nw  = gridDim.x * 4;

    for (int s = 0; s < NSWEEP; s++) {
        for (int n = wid; n < NN; n += nw) {
            const int i   = s * NN + n;
            const int beg = (i == 0) ? 0 : cursor[i - 1];   // segments contiguous post-scatter
            const int end = cursor[i];
            if (s > 0 && beg == end) continue;
            float agg = (s == 0) ? 0.0f
                                 : __half2float(aggh[(size_t)n * 64 + d]);
            agg = seg_accum<BF16>(xv, recs_eid, recs_src, eav, we, bed,
                                  beg, end, d, agg);
            aggh[(size_t)n * 64 + d] = __float2half(agg);
        }
    }
}

__global__ __launch_bounds__(256) void gather_agg_kernel(
    const void* x, const int* recs_eid, const unsigned short* recs_src,
    const int* cursor, const void* ea, const void* We, const void* be,
    __half* aggh, const int* flag)
{
    if (*flag) gather_body<true >(x, recs_eid, recs_src, cursor, ea, We, be, aggh);
    else       gather_body<false>(x, recs_eid, recs_src, cursor, ea, We, be, aggh);
}

// ---------------- MLP (unchanged from measured-best version) ----------------
template <bool BF16>
__device__ __forceinline__ void mlp_body(
    const void* __restrict__ xv, const __half* __restrict__ aggh,
    const void* __restrict__ W1v, const void* __restrict__ b1v,
    const void* __restrict__ W2v, const void* __restrict__ b2v,
    void* __restrict__ outv, float (*sh)[64], float (*st)[64])
{
    const int tid = threadIdx.x;
    const int d   = tid & 63;
    const int w   = tid >> 6;

    float w1c[64], w2c[64], b1d, b2d;
    if constexpr (BF16) {
        const __hip_bfloat16* W1 = (const __hip_bfloat16*)W1v;
        const __hip_bfloat16* W2 = (const __hip_bfloat16*)W2v;
#pragma unroll
        for (int k = 0; k < 64; k++) {
            w1c[k] = __bfloat162float(W1[k * 64 + d]);
            w2c[k] = __bfloat162float(W2[k * 64 + d]);
        }
        b1d = __bfloat162float(((const __hip_bfloat16*)b1v)[d]);
        b2d = __bfloat162float(((const __hip_bfloat16*)b2v)[d]);
    } else {
        const float* W1 = (const float*)W1v;
        const float* W2 = (const float*)W2v;
#pragma unroll
        for (int k = 0; k < 64; k++) {
            w1c[k] = W1[k * 64 + d];
            w2c[k] = W2[k * 64 + d];
        }
        b1d = ((const float*)b1v)[d];
        b2d = ((const float*)b2v)[d];
    }

    const int stride = gridDim.x * 4;
    int node = blockIdx.x * 4 + w;

    float xs_n = 0.0f, ag_n = 0.0f;
    if (node < NN) {
        if constexpr (BF16) xs_n = __bfloat162float(((const __hip_bfloat16*)xv)[(size_t)node * 64 + d]);
        else                xs_n = ((const float*)xv)[(size_t)node * 64 + d];
        ag_n = __half2float(aggh[(size_t)node * 64 + d]);
    }

    while (node < NN) {
        const float xs_c = xs_n, ag_c = ag_n;
        const int next = node + stride;
        if (next < NN) {
            if constexpr (BF16) xs_n = __bfloat162float(((const __hip_bfloat16*)xv)[(size_t)next * 64 + d]);
            else                xs_n = ((const float*)xv)[(size_t)next * 64 + d];
            ag_n = __half2float(aggh[(size_t)next * 64 + d]);
        }

        sh[w][d] = xs_c + ag_c;

        float t = b1d;
        const float4* hv = (const float4*)sh[w];
#pragma unroll
        for (int k = 0; k < 16; k++) {
            const float4 hq = hv[k];
            t = fmaf(hq.x, w1c[4 * k],     t);
            t = fmaf(hq.y, w1c[4 * k + 1], t);
            t = fmaf(hq.z, w1c[4 * k + 2], t);
            t = fmaf(hq.w, w1c[4 * k + 3], t);
        }
        t = fmaxf(t, 0.0f);
        st[w][d] = t;

        float o = b2d;
        const float4* tv = (const float4*)st[w];
#pragma unroll
        for (int k = 0; k < 16; k++) {
            const float4 tq = tv[k];
            o = fmaf(tq.x, w2c[4 * k],     o);
            o = fmaf(tq.y, w2c[4 * k + 1], o);
            o = fmaf(tq.z, w2c[4 * k + 2], o);
            o = fmaf(tq.w, w2c[4 * k + 3], o);
        }
        if constexpr (BF16) ((__hip_bfloat16*)outv)[(size_t)node * 64 + d] = __float2bfloat16(o);
        else                ((float*)outv)[(size_t)node * 64 + d] = o;
        node = next;
    }
}

__global__ __launch_bounds__(256) void mlp_kernel(
    const void* x, const __half* aggh,
    const void* W1, const void* b1, const void* W2, const void* b2,
    void* out, const int* flag)
{
    __shared__ float sh[4][64];
    __shared__ float st[4][64];
    if (*flag) mlp_body<true >(x, aggh, W1, b1, W2, b2, out, sh, st);
    else       mlp_body<false>(x, aggh, W1, b1, W2, b2, out, sh, st);
}

extern "C" void kernel_launch(void* const* d_in, const int* in_sizes, int n_in,
                              void* d_out, int out_size, void* d_ws, size_t ws_size,
                              hipStream_t stream) {
    const void* x          = d_in[0];
    const int*  edge_index = (const int*)d_in[1];
    const void* edge_attr  = d_in[2];
    const void* We         = d_in[3];
    const void* be         = d_in[4];
    const void* W1         = d_in[5];
    const void* b1         = d_in[6];
    const void* W2         = d_in[7];
    const void* b2         = d_in[8];

    char* ws = (char*)d_ws;
    __half*         aggh   = (__half*)(ws + OFF_AGGH);
    int*            eid    = (int*)(ws + OFF_EID);
    unsigned short* rsrc   = (unsigned short*)(ws + OFF_SRC);
    int*            cursor = (int*)(ws + OFF_CURSOR);
    int*            part   = (int*)(ws + OFF_PART);
    int*            flag   = (int*)(ws + OFF_FLAG);

    hipLaunchKernelGGL(zero_detect_kernel, dim3(SCAN_BLKS), dim3(256), 0, stream,
                       (const unsigned*)x, cursor, flag);
    hipLaunchKernelGGL(hist_kernel, dim3((EE + 255) / 256), dim3(256), 0, stream,
                       edge_index, cursor);
    hipLaunchKernelGGL(scanA_kernel, dim3(SCAN_BLKS), dim3(256), 0, stream,
                       cursor, part);
    hipLaunchKernelGGL(scanBC_kernel, dim3(SCAN_BLKS), dim3(256), 0, stream,
                       part, cursor);
    hipLaunchKernelGGL(scatter_kernel, dim3((EE + 255) / 256), dim3(256), 0, stream,
                       edge_index, cursor, eid, rsrc);
    hipLaunchKernelGGL(gather_agg_kernel, dim3(2048), dim3(256), 0, stream,
                       x, eid, rsrc, cursor, edge_attr, We, be, aggh, flag);
    hipLaunchKernelGGL(mlp_kernel, dim3(768), dim3(256), 0, stream,
                       x, aggh, W1, b1, W2, b2, d_out, flag);
}

// Round 6
// 275.400 us; speedup vs baseline: 1.3639x; 1.3639x over previous
//
#include <hip/hip_runtime.h>
#include <hip/hip_fp16.h>
#include <hip/hip_bf16.h>

#define NN 50000
#define EE 800000
#define NSLICE 8
#define SLICE 6250            // 50000/8; x slice = 6250*128B = 0.8MB << 4MB XCD L2
#define NCHUNK 256
#define CHUNK 3125            // EE / NCHUNK exactly
#define WQ 784                // per-wave LDS queue capacity (>= ceil(3125/4)=782)

// ---- workspace layout (proven-safe 12.8MB + flag envelope) ----
#define OFF_AGGH 0ull            // 50000*64*2 = 6,400,000
#define OFF_SD   6400000ull      // 800000*4  = 3,200,000 -> ends 9,600,000
#define OFF_FLAG 12800000ull     // proven-safe flag offset

__device__ __forceinline__ float bflo(unsigned u) { return __uint_as_float(u << 16); }
__device__ __forceinline__ float bfhi(unsigned u) { return __uint_as_float(u & 0xffff0000u); }

// flag=1 if float tensors are bf16, 0 if f32 (proven R3/R6 of prior session).
__global__ void detect_dtype(const unsigned* __restrict__ xw, int* __restrict__ flag) {
    const int t = threadIdx.x;  // 64 threads
    unsigned e = (xw[t] >> 7) & 0xFFu;
    unsigned long long m = __ballot(e >= 100u && e <= 140u);
    if (t == 0) *flag = (__popcll(m) >= 32) ? 1 : 0;
}

// pack (src,dst) into one uint each: src | dst<<16  (both < 65536)
__global__ __launch_bounds__(256) void pack_kernel(const int* __restrict__ ei,
                                                   unsigned* __restrict__ sd) {
    const int oddor = ei[1] | ei[3] | ei[5] | ei[7] | ei[9] | ei[11] | ei[13] | ei[15];
    const bool idx64 = (oddor == 0);
    const long long* __restrict__ ei64 = (const long long*)ei;
    const int e = blockIdx.x * 256 + threadIdx.x;   // grid covers EE exactly
    int src, dst;
    if (idx64) { src = (int)ei64[e]; dst = (int)ei64[EE + e]; }
    else       { src = ei[e];        dst = ei[EE + e]; }
    sd[e] = (unsigned)src | ((unsigned)dst << 16);
}

// edge_attr row (wave-broadcast) dot We column — plain cached loads (R3: never nt)
template <bool BF16>
__device__ __forceinline__ float edge_lin(const void* __restrict__ eav, int e,
                                          const float* __restrict__ we, float bed) {
    float acc = bed;
    if constexpr (BF16) {
        const uint4* row = (const uint4*)((const __hip_bfloat16*)eav + (size_t)e * 16);
        const uint4 p0 = row[0];
        const uint4 p1 = row[1];
        acc = fmaf(bflo(p0.x), we[0],  acc); acc = fmaf(bfhi(p0.x), we[1],  acc);
        acc = fmaf(bflo(p0.y), we[2],  acc); acc = fmaf(bfhi(p0.y), we[3],  acc);
        acc = fmaf(bflo(p0.z), we[4],  acc); acc = fmaf(bfhi(p0.z), we[5],  acc);
        acc = fmaf(bflo(p0.w), we[6],  acc); acc = fmaf(bfhi(p0.w), we[7],  acc);
        acc = fmaf(bflo(p1.x), we[8],  acc); acc = fmaf(bfhi(p1.x), we[9],  acc);
        acc = fmaf(bflo(p1.y), we[10], acc); acc = fmaf(bfhi(p1.y), we[11], acc);
        acc = fmaf(bflo(p1.z), we[12], acc); acc = fmaf(bfhi(p1.z), we[13], acc);
        acc = fmaf(bflo(p1.w), we[14], acc); acc = fmaf(bfhi(p1.w), we[15], acc);
    } else {
        const float4* row = (const float4*)((const float*)eav + (size_t)e * 16);
        const float4 q0 = row[0], q1 = row[1], q2 = row[2], q3 = row[3];
        acc = fmaf(q0.x, we[0],  acc); acc = fmaf(q0.y, we[1],  acc);
        acc = fmaf(q0.z, we[2],  acc); acc = fmaf(q0.w, we[3],  acc);
        acc = fmaf(q1.x, we[4],  acc); acc = fmaf(q1.y, we[5],  acc);
        acc = fmaf(q1.z, we[6],  acc); acc = fmaf(q1.w, we[7],  acc);
        acc = fmaf(q2.x, we[8],  acc); acc = fmaf(q2.y, we[9],  acc);
        acc = fmaf(q2.z, we[10], acc); acc = fmaf(q2.w, we[11], acc);
        acc = fmaf(q3.x, we[12], acc); acc = fmaf(q3.y, we[13], acc);
        acc = fmaf(q3.z, we[14], acc); acc = fmaf(q3.w, we[15], acc);
    }
    return acc;
}

template <bool BF16>
__device__ __forceinline__ float loadx(const void* __restrict__ xv, int s, int d) {
    if constexpr (BF16)
        return __bfloat162float(((const __hip_bfloat16*)xv)[(size_t)s * 64 + d]);
    else
        return ((const float*)xv)[(size_t)s * 64 + d];
}

// process one owned edge: msg = relu(x[src]+ea@We+be); pk-f16 atomic into aggh[dst]
template <bool BF16>
__device__ __forceinline__ void do_edge(
    const void* __restrict__ xv, const void* __restrict__ eav,
    const float* __restrict__ we, float bed, __half2* __restrict__ aggh,
    int src, int dst, int eid, int d)
{
    const float xs  = loadx<BF16>(xv, src, d);
    const float a   = edge_lin<BF16>(eav, eid, we, bed);
    const float msg = fmaxf(a + xs, 0.0f);
    const float oth = __shfl_xor(msg, 1);
    if ((d & 1) == 0) {
        __half2 v = __floats2half2_rn(msg, oth);
        unsafeAtomicAdd(aggh + (size_t)dst * 32 + (d >> 1), v);
    }
}

// ---- XCD-sliced edge aggregation ----
// block g: slice p = g%8 (XCD-confined x reads), chunk c = g/8.
// pass1: lane-parallel ballot-compact owned edges into per-wave LDS queue.
// pass2: proven 4-wide ILP body over the compacted list, pk-f16 atomics.
template <bool BF16>
__device__ __forceinline__ void slice_body(
    const void* __restrict__ xv, const unsigned* __restrict__ sd,
    const void* __restrict__ eav, const void* __restrict__ Wev,
    const void* __restrict__ bev, __half2* __restrict__ aggh,
    uint2 (*q)[WQ])
{
    const int tid  = threadIdx.x;
    const int d    = tid & 63;
    const int sub  = tid >> 6;
    const int p    = blockIdx.x & 7;
    const int c    = blockIdx.x >> 3;

    float we[16];
    float bed;
    if constexpr (BF16) {
        const __hip_bfloat16* We = (const __hip_bfloat16*)Wev;
#pragma unroll
        for (int k = 0; k < 16; k++) we[k] = __bfloat162float(We[k * 64 + d]);
        bed = __bfloat162float(((const __hip_bfloat16*)bev)[d]);
    } else {
        const float* We = (const float*)Wev;
#pragma unroll
        for (int k = 0; k < 16; k++) we[k] = We[k * 64 + d];
        bed = ((const float*)bev)[d];
    }

    // wave's sub-range of the chunk
    const int cb = c * CHUNK;
    const int a0 = cb + sub * 782;
    const int a1 = cb + min(CHUNK, (sub + 1) * 782);

    // ---- pass 1: ballot-compact owned edges (coalesced srcdst scan) ----
    int cnt = 0;
    for (int base = a0; base < a1; base += 64) {
        const int e = base + d;
        unsigned v = 0;
        bool own = false;
        if (e < a1) {
            v = sd[e];
            own = ((int)(v & 0xFFFFu) / SLICE) == p;
        }
        const unsigned long long m = __ballot(own);
        if (own) {
            const int rank = __popcll(m & ((1ull << d) - 1ull));
            q[sub][cnt + rank] = make_uint2(v, (unsigned)e);
        }
        cnt += __popcll(m);
    }

    // ---- pass 2: 4-wide over compacted list ----
    int k = 0;
    for (; k + 4 <= cnt; k += 4) {
        const uint2 r0 = q[sub][k],     r1 = q[sub][k + 1];
        const uint2 r2 = q[sub][k + 2], r3 = q[sub][k + 3];
        const int s0 = r0.x & 0xFFFFu, t0 = r0.x >> 16, e0 = (int)r0.y;
        const int s1 = r1.x & 0xFFFFu, t1 = r1.x >> 16, e1 = (int)r1.y;
        const int s2 = r2.x & 0xFFFFu, t2 = r2.x >> 16, e2 = (int)r2.y;
        const int s3 = r3.x & 0xFFFFu, t3 = r3.x >> 16, e3 = (int)r3.y;
        const float x0 = loadx<BF16>(xv, s0, d);
        const float x1 = loadx<BF16>(xv, s1, d);
        const float x2 = loadx<BF16>(xv, s2, d);
        const float x3 = loadx<BF16>(xv, s3, d);
        const float a0f = edge_lin<BF16>(eav, e0, we, bed);
        const float a1f = edge_lin<BF16>(eav, e1, we, bed);
        const float a2f = edge_lin<BF16>(eav, e2, we, bed);
        const float a3f = edge_lin<BF16>(eav, e3, we, bed);
        const float m0 = fmaxf(a0f + x0, 0.0f);
        const float m1 = fmaxf(a1f + x1, 0.0f);
        const float m2 = fmaxf(a2f + x2, 0.0f);
        const float m3 = fmaxf(a3f + x3, 0.0f);
        const float o0 = __shfl_xor(m0, 1);
        const float o1 = __shfl_xor(m1, 1);
        const float o2 = __shfl_xor(m2, 1);
        const float o3 = __shfl_xor(m3, 1);
        if ((d & 1) == 0) {
            const int h = d >> 1;
            unsafeAtomicAdd(aggh + (size_t)t0 * 32 + h, __floats2half2_rn(m0, o0));
            unsafeAtomicAdd(aggh + (size_t)t1 * 32 + h, __floats2half2_rn(m1, o1));
            unsafeAtomicAdd(aggh + (size_t)t2 * 32 + h, __floats2half2_rn(m2, o2));
            unsafeAtomicAdd(aggh + (size_t)t3 * 32 + h, __floats2half2_rn(m3, o3));
        }
    }
    for (; k < cnt; ++k) {
        const uint2 r = q[sub][k];
        do_edge<BF16>(xv, eav, we, bed, aggh,
                      (int)(r.x & 0xFFFFu), (int)(r.x >> 16), (int)r.y, d);
    }
}

__global__ __launch_bounds__(256) void slice_agg_kernel(
    const void* x, const unsigned* sd, const void* ea,
    const void* We, const void* be, __half2* aggh, const int* flag)
{
    __shared__ uint2 q[4][WQ];
    if (*flag) slice_body<true >(x, sd, ea, We, be, aggh, q);
    else       slice_body<false>(x, sd, ea, We, be, aggh, q);
}

// ---------------- MLP (unchanged from measured-best version) ----------------
template <bool BF16>
__device__ __forceinline__ void mlp_body(
    const void* __restrict__ xv, const __half* __restrict__ aggh,
    const void* __restrict__ W1v, const void* __restrict__ b1v,
    const void* __restrict__ W2v, const void* __restrict__ b2v,
    void* __restrict__ outv, float (*sh)[64], float (*st)[64])
{
    const int tid = threadIdx.x;
    const int d   = tid & 63;
    const int w   = tid >> 6;

    float w1c[64], w2c[64], b1d, b2d;
    if constexpr (BF16) {
        const __hip_bfloat16* W1 = (const __hip_bfloat16*)W1v;
        const __hip_bfloat16* W2 = (const __hip_bfloat16*)W2v;
#pragma unroll
        for (int k = 0; k < 64; k++) {
            w1c[k] = __bfloat162float(W1[k * 64 + d]);
            w2c[k] = __bfloat162float(W2[k * 64 + d]);
        }
        b1d = __bfloat162float(((const __hip_bfloat16*)b1v)[d]);
        b2d = __bfloat162float(((const __hip_bfloat16*)b2v)[d]);
    } else {
        const float* W1 = (const float*)W1v;
        const float* W2 = (const float*)W2v;
#pragma unroll
        for (int k = 0; k < 64; k++) {
            w1c[k] = W1[k * 64 + d];
            w2c[k] = W2[k * 64 + d];
        }
        b1d = ((const float*)b1v)[d];
        b2d = ((const float*)b2v)[d];
    }

    const int stride = gridDim.x * 4;
    int node = blockIdx.x * 4 + w;

    float xs_n = 0.0f, ag_n = 0.0f;
    if (node < NN) {
        if constexpr (BF16) xs_n = __bfloat162float(((const __hip_bfloat16*)xv)[(size_t)node * 64 + d]);
        else                xs_n = ((const float*)xv)[(size_t)node * 64 + d];
        ag_n = __half2float(aggh[(size_t)node * 64 + d]);
    }

    while (node < NN) {
        const float xs_c = xs_n, ag_c = ag_n;
        const int next = node + stride;
        if (next < NN) {
            if constexpr (BF16) xs_n = __bfloat162float(((const __hip_bfloat16*)xv)[(size_t)next * 64 + d]);
            else                xs_n = ((const float*)xv)[(size_t)next * 64 + d];
            ag_n = __half2float(aggh[(size_t)next * 64 + d]);
        }

        sh[w][d] = xs_c + ag_c;

        float t = b1d;
        const float4* hv = (const float4*)sh[w];
#pragma unroll
        for (int k = 0; k < 16; k++) {
            const float4 hq = hv[k];
            t = fmaf(hq.x, w1c[4 * k],     t);
            t = fmaf(hq.y, w1c[4 * k + 1], t);
            t = fmaf(hq.z, w1c[4 * k + 2], t);
            t = fmaf(hq.w, w1c[4 * k + 3], t);
        }
        t = fmaxf(t, 0.0f);
        st[w][d] = t;

        float o = b2d;
        const float4* tv = (const float4*)st[w];
#pragma unroll
        for (int k = 0; k < 16; k++) {
            const float4 tq = tv[k];
            o = fmaf(tq.x, w2c[4 * k],     o);
            o = fmaf(tq.y, w2c[4 * k + 1], o);
            o = fmaf(tq.z, w2c[4 * k + 2], o);
            o = fmaf(tq.w, w2c[4 * k + 3], o);
        }
        if constexpr (BF16) ((__hip_bfloat16*)outv)[(size_t)node * 64 + d] = __float2bfloat16(o);
        else                ((float*)outv)[(size_t)node * 64 + d] = o;
        node = next;
    }
}

__global__ __launch_bounds__(256) void mlp_kernel(
    const void* x, const __half* aggh,
    const void* W1, const void* b1, const void* W2, const void* b2,
    void* out, const int* flag)
{
    __shared__ float sh[4][64];
    __shared__ float st[4][64];
    if (*flag) mlp_body<true >(x, aggh, W1, b1, W2, b2, out, sh, st);
    else       mlp_body<false>(x, aggh, W1, b1, W2, b2, out, sh, st);
}

extern "C" void kernel_launch(void* const* d_in, const int* in_sizes, int n_in,
                              void* d_out, int out_size, void* d_ws, size_t ws_size,
                              hipStream_t stream) {
    const void* x          = d_in[0];
    const int*  edge_index = (const int*)d_in[1];
    const void* edge_attr  = d_in[2];
    const void* We         = d_in[3];
    const void* be         = d_in[4];
    const void* W1         = d_in[5];
    const void* b1         = d_in[6];
    const void* W2         = d_in[7];
    const void* b2         = d_in[8];

    char* ws = (char*)d_ws;
    __half*   aggh = (__half*)(ws + OFF_AGGH);
    unsigned* sd   = (unsigned*)(ws + OFF_SD);
    int*      flag = (int*)(ws + OFF_FLAG);

    hipMemsetAsync(aggh, 0, (size_t)NN * 64 * sizeof(__half), stream);
    hipLaunchKernelGGL(detect_dtype, dim3(1), dim3(64), 0, stream,
                       (const unsigned*)x, flag);
    hipLaunchKernelGGL(pack_kernel, dim3(EE / 256), dim3(256), 0, stream,
                       edge_index, sd);
    hipLaunchKernelGGL(slice_agg_kernel, dim3(NSLICE * NCHUNK), dim3(256), 0, stream,
                       x, sd, edge_attr, We, be, (__half2*)aggh, flag);
    hipLaunchKernelGGL(mlp_kernel, dim3(768), dim3(256), 0, stream,
                       x, aggh, W1, b1, W2, b2, d_out, flag);
}